// Round 9
// baseline (229.896 us; speedup 1.0000x reference)
//
#include <hip/hip_runtime.h>
#include <hip/hip_bf16.h>

typedef __bf16 bf16_t;
typedef __bf16 bf16x4 __attribute__((ext_vector_type(4)));
typedef __bf16 bf16x8 __attribute__((ext_vector_type(8)));
typedef float floatx16 __attribute__((ext_vector_type(16)));

#define SEQ    8192
#define DM     1024
#define NHEADS 16
#define HDIM   64

// async global->LDS, 16B per lane; LDS dest is wave-uniform base + lane*16
__device__ __forceinline__ void async_ld16(bf16_t* lds, const bf16_t* g) {
  __builtin_amdgcn_global_load_lds(
      (__attribute__((address_space(1))) void*)g,
      (__attribute__((address_space(3))) void*)lds, 16, 0, 0);
}

// one launch converts x (8192 blocks) + 4 weight matrices (1024 blocks each)
__global__ __launch_bounds__(256)
void cvt_all(const float* __restrict__ x,  const float* __restrict__ qw,
             const float* __restrict__ kw, const float* __restrict__ vw,
             const float* __restrict__ ow,
             bf16_t* __restrict__ Xb,  bf16_t* __restrict__ QWb,
             bf16_t* __restrict__ KWb, bf16_t* __restrict__ VWb,
             bf16_t* __restrict__ OWb) {
  const int b = blockIdx.x;
  const float* in; bf16_t* out; int g;
  if (b < 8192) { in = x; out = Xb; g = b; }
  else {
    const int w  = (b - 8192) >> 10;
    const int wb = (b - 8192) & 1023;
    switch (w) {
      case 0:  in = qw; out = QWb; break;
      case 1:  in = kw; out = KWb; break;
      case 2:  in = vw; out = VWb; break;
      default: in = ow; out = OWb; break;
    }
    g = wb;
  }
  const int idx = (g * 256 + threadIdx.x) * 4;
  float4 v = *(const float4*)(in + idx);
  bf16x4 o = { (bf16_t)v.x, (bf16_t)v.y, (bf16_t)v.z, (bf16_t)v.w };
  *(bf16x4*)(out + idx) = o;
}

// ---------- Verified 128x128 single-buffer GEMM core (845 TF class) ----------
// 128x128 tile, BK=64, 4 waves (wave tile 64x64), 32KB LDS, 80 VGPR ->
// ~5 co-resident blocks/CU; drain stall at __syncthreads hidden by
// INTER-BLOCK overlap (m114). GEMM ledger (rounds 1-4,7): 6/6 variants that
// reduced blocks/CU (bigger tile, dbuf 64KB, in-flight vmcnt schedules)
// regressed. This structure is the accepted local optimum; DO NOT add
// double-buffering or grow the wave tile without a new mechanism.
// LDS XOR-8 swizzle: slot c of row r holds global chunk c^(r&7).
// A/B frag: m=lane&31, k=(lane>>5)*8+j. C/D: col=lane&31,
// row=(reg&3)+8*(reg>>2)+4*(lane>>5)  [m74/m101].
template <typename OutT>
__device__ __forceinline__ void gemm128_core(
    const bf16_t* __restrict__ A, const bf16_t* __restrict__ B,
    OutT* __restrict__ C, float scl)
{
  constexpr int Kdim = DM;
  __shared__ __attribute__((aligned(16))) bf16_t sA[128 * 64];   // 16 KB
  __shared__ __attribute__((aligned(16))) bf16_t sB[128 * 64];   // 16 KB

  const int tid  = threadIdx.x;
  const int wave = tid >> 6;
  const int lane = tid & 63;
  const int l31  = lane & 31;
  const int half = lane >> 5;
  const int wr   = (wave >> 1) * 64;
  const int wc   = (wave & 1) * 64;

  const int gc = (lane & 7) ^ ((lane >> 3) & 7);   // swizzled fetch chunk
  const size_t arow0 = (size_t)blockIdx.x * 128 + wave * 32 + (lane >> 3);
  const size_t brow0 = (size_t)blockIdx.y * 128 + wave * 32 + (lane >> 3);
  const bf16_t* Ag = A + arow0 * Kdim + gc * 8;
  const bf16_t* Bg = B + brow0 * Kdim + gc * 8;
  bf16_t* sAw = sA + wave * 32 * 64;
  bf16_t* sBw = sB + wave * 32 * 64;

  floatx16 acc[2][2];
  #pragma unroll
  for (int i = 0; i < 2; ++i)
    #pragma unroll
    for (int j = 0; j < 2; ++j)
      acc[i][j] = (floatx16)(0.0f);

  const int sw = l31 & 7;                 // read-side swizzle key

  for (int ko = 0; ko < Kdim; ko += 64) {
    #pragma unroll
    for (int n = 0; n < 4; ++n) {
      async_ld16(sAw + n * 512, Ag + (size_t)n * 8 * Kdim + ko);
      async_ld16(sBw + n * 512, Bg + (size_t)n * 8 * Kdim + ko);
    }
    __syncthreads();   // drains vmcnt, then barrier

    #pragma unroll
    for (int s = 0; s < 4; ++s) {         // four K=16 sub-steps
      const int ck   = s * 2 + half;
      const int slot = (ck ^ sw) * 8;
      bf16x8 af[2], bfr[2];
      #pragma unroll
      for (int mi = 0; mi < 2; ++mi)
        af[mi] = *(const bf16x8*)&sA[(wr + mi * 32 + l31) * 64 + slot];
      #pragma unroll
      for (int ni = 0; ni < 2; ++ni)
        bfr[ni] = *(const bf16x8*)&sB[(wc + ni * 32 + l31) * 64 + slot];

      #pragma unroll
      for (int mi = 0; mi < 2; ++mi)
        #pragma unroll
        for (int ni = 0; ni < 2; ++ni)
          acc[mi][ni] = __builtin_amdgcn_mfma_f32_32x32x16_bf16(af[mi], bfr[ni], acc[mi][ni], 0, 0, 0);
    }

    __syncthreads();   // protect LDS before next stage overwrites
  }

  const int crow0 = blockIdx.x * 128 + wr + 4 * half;
  const int ccol0 = blockIdx.y * 128 + wc + l31;
  #pragma unroll
  for (int mi = 0; mi < 2; ++mi)
    #pragma unroll
    for (int ni = 0; ni < 2; ++ni)
      #pragma unroll
      for (int r = 0; r < 16; ++r) {
        const int row = crow0 + mi * 32 + (r & 3) + 8 * (r >> 2);
        C[(size_t)row * DM + (ccol0 + ni * 32)] = (OutT)(acc[mi][ni][r] * scl);
      }
}

__global__ __launch_bounds__(256)
void gemm_proj(const bf16_t* __restrict__ A, const bf16_t* __restrict__ B,
               bf16_t* __restrict__ C, float scl)
{
  gemm128_core<bf16_t>(A, B, C, scl);
}

__global__ __launch_bounds__(256)
void gemm_outk(const bf16_t* __restrict__ A, const bf16_t* __restrict__ B,
               float* __restrict__ C)
{
  gemm128_core<float>(A, B, C, 1.0f);
}

// ---------- Attention: FULL-SCORE (non-online) softmax, max-MLP (round 9) ----------
// Round-7 counters: FETCH 103MB served at only 2.8 TB/s with VALUBusy 35% ->
// memory-LATENCY/MLP-limited, not BW- or VALU-limited. Root cause: online
// softmax serializes the <=14 positions into a dependent chain (<=4 loads in
// flight/wave). npos<=14 means ALL scores fit in registers -> classic 3-phase
// softmax with ZERO cross-position dependencies:
//   (1) 14 unconditional independent K-row loads + dots (invalid t clamps to
//       base = row i, whose dot == sc[0], so unguarded max == valid max);
//   (2) tree-max, independent exps, masked (w[t]=0) sum;
//   (3) 14 independent V-row loads + weighted accumulate.
// 28 independent 256B wave-loads in flight (vs ~4) -> latency hidden by MLP,
// not occupancy. Addresses fold to base - const (2^(t-1)*DM compile-time).
// 1 wave/query, 4 queries/block, no LDS, no barriers. Balanced XCD interleave
// (round 8): XCD x gets chunks {x, 8+x, 16+x, 24+x} of 256 queries -> equal
// sum-npos per XCD. Lane L owns dims [16L,16L+16); Q arrives pre-scaled.
__global__ __launch_bounds__(256)
void dilated_attn(const bf16_t* __restrict__ Q, const bf16_t* __restrict__ K,
                  const bf16_t* __restrict__ V, bf16_t* O)
{
  const int lane = threadIdx.x & 63;
  const int wv   = threadIdx.x >> 6;   // 0..3
  const int bid  = blockIdx.x;         // 0..2047
  const int jj   = bid >> 3;
  const int chunk= (bid & 7) + ((jj >> 6) << 3);       // 0..31
  const int i    = chunk * 256 + (jj & 63) * 4 + wv;   // query index
  const size_t base = (size_t)i * DM + lane * 16;

  bf16x8 q0 = *(const bf16x8*)(Q + base);
  bf16x8 q1 = *(const bf16x8*)(Q + base + 8);
  float qf[16];
  #pragma unroll
  for (int j = 0; j < 8; ++j) { qf[j] = (float)q0[j]; qf[j + 8] = (float)q1[j]; }

  // npos = 1 (i==0) else floor(log2 i) + 2  (wave-uniform); max 14 at SEQ=8192
  const int npos = (i == 0) ? 1 : (33 - __builtin_clz((unsigned)i));

  // ---- phase 1: all scores (14 independent load+dot chains) ----
  float sc[14];
  #pragma unroll
  for (int t = 0; t < 14; ++t) {
    const size_t back = (t == 0) ? 0 : ((size_t)(1u << (t - 1)) * DM);  // const
    const size_t a = base - ((t < npos) ? back : 0);   // invalid -> row i
    const bf16x8 k0 = *(const bf16x8*)(K + a);
    const bf16x8 k1 = *(const bf16x8*)(K + a + 8);
    float s = 0.0f;
    #pragma unroll
    for (int j = 0; j < 8; ++j) s += qf[j] * (float)k0[j] + qf[j + 8] * (float)k1[j];
    s += __shfl_xor(s, 1, 64);           // sum across the 4 lanes of this head
    s += __shfl_xor(s, 2, 64);
    sc[t] = s;
  }

  // ---- phase 2: softmax over <=14 registers (tree max; masked sum) ----
  // invalid sc[t] == sc[0] exactly, so unguarded max is safe.
  float m01 = fmaxf(sc[0], sc[1]),  m23 = fmaxf(sc[2], sc[3]);
  float m45 = fmaxf(sc[4], sc[5]),  m67 = fmaxf(sc[6], sc[7]);
  float m89 = fmaxf(sc[8], sc[9]),  mab = fmaxf(sc[10], sc[11]);
  float mcd = fmaxf(sc[12], sc[13]);
  float m = fmaxf(fmaxf(fmaxf(m01, m23), fmaxf(m45, m67)),
                  fmaxf(fmaxf(m89, mab), mcd));
  float w[14];
  #pragma unroll
  for (int t = 0; t < 14; ++t) {
    const float e = __expf(sc[t] - m);
    w[t] = (t < npos) ? e : 0.0f;        // mask invalid positions
  }
  float l01 = w[0]+w[1], l23 = w[2]+w[3], l45 = w[4]+w[5], l67 = w[6]+w[7];
  float l89 = w[8]+w[9], lab = w[10]+w[11], lcd = w[12]+w[13];
  const float l = ((l01+l23)+(l45+l67)) + ((l89+lab)+lcd);

  // ---- phase 3: weighted V sum (14 independent loads; 16 indep FMA chains) ----
  float acc[16];
  #pragma unroll
  for (int j = 0; j < 16; ++j) acc[j] = 0.0f;
  #pragma unroll
  for (int t = 0; t < 14; ++t) {
    const size_t back = (t == 0) ? 0 : ((size_t)(1u << (t - 1)) * DM);
    const size_t a = base - ((t < npos) ? back : 0);
    const bf16x8 v0 = *(const bf16x8*)(V + a);
    const bf16x8 v1 = *(const bf16x8*)(V + a + 8);
    #pragma unroll
    for (int j = 0; j < 8; ++j) {
      acc[j]     += w[t] * (float)v0[j];
      acc[j + 8] += w[t] * (float)v1[j];
    }
  }

  const float inv = 1.0f / l;
  bf16x8 o0, o1;
  #pragma unroll
  for (int j = 0; j < 8; ++j) {
    o0[j] = (bf16_t)(acc[j]     * inv);
    o1[j] = (bf16_t)(acc[j + 8] * inv);
  }
  *(bf16x8*)(O + base)     = o0;
  *(bf16x8*)(O + base + 8) = o1;
}

extern "C" void kernel_launch(void* const* d_in, const int* in_sizes, int n_in,
                              void* d_out, int out_size, void* d_ws, size_t ws_size,
                              hipStream_t stream) {
  (void)in_sizes; (void)n_in; (void)out_size; (void)ws_size;
  const float* x  = (const float*)d_in[0];
  const float* qw = (const float*)d_in[1];
  const float* kw = (const float*)d_in[2];
  const float* vw = (const float*)d_in[3];
  const float* ow = (const float*)d_in[4];
  // d_in[5] (positions) and d_in[6] (attend_mask) recomputed analytically in-kernel
  float* out = (float*)d_out;

  bf16_t* Xb  = (bf16_t*)d_ws;                       // 8192x1024
  bf16_t* Qb  = Xb  + (size_t)SEQ * DM;
  bf16_t* Kb  = Qb  + (size_t)SEQ * DM;
  bf16_t* Vb  = Kb  + (size_t)SEQ * DM;
  bf16_t* QWb = Vb  + (size_t)SEQ * DM;              // 1024x1024 x4
  bf16_t* KWb = QWb + (size_t)DM * DM;
  bf16_t* VWb = KWb + (size_t)DM * DM;
  bf16_t* OWb = VWb + (size_t)DM * DM;
  bf16_t* AO  = Qb;  // alias Q: each attn wave reads its own q row before writing it

  cvt_all<<<dim3(8192 + 4096), dim3(256), 0, stream>>>(x, qw, kw, vw, ow,
                                                       Xb, QWb, KWb, VWb, OWb);

  dim3 pg(SEQ / 128, DM / 128);
  gemm_proj<<<pg, dim3(256), 0, stream>>>(Xb, QWb, Qb, 0.125f);  // fold 1/sqrt(64)
  gemm_proj<<<pg, dim3(256), 0, stream>>>(Xb, KWb, Kb, 1.0f);
  gemm_proj<<<pg, dim3(256), 0, stream>>>(Xb, VWb, Vb, 1.0f);
  dilated_attn<<<dim3(SEQ / 4), dim3(256), 0, stream>>>(Qb, Kb, Vb, AO);
  gemm_outk<<<pg, dim3(256), 0, stream>>>(AO, OWb, out);
}

// Round 10
// 226.279 us; speedup vs baseline: 1.0160x; 1.0160x over previous
//
#include <hip/hip_runtime.h>
#include <hip/hip_bf16.h>

typedef __bf16 bf16_t;
typedef __bf16 bf16x4 __attribute__((ext_vector_type(4)));
typedef __bf16 bf16x8 __attribute__((ext_vector_type(8)));
typedef float floatx16 __attribute__((ext_vector_type(16)));

#define SEQ    8192
#define DM     1024
#define NHEADS 16
#define HDIM   64

// async global->LDS, 16B per lane; LDS dest is wave-uniform base + lane*16
__device__ __forceinline__ void async_ld16(bf16_t* lds, const bf16_t* g) {
  __builtin_amdgcn_global_load_lds(
      (__attribute__((address_space(1))) void*)g,
      (__attribute__((address_space(3))) void*)lds, 16, 0, 0);
}

// one launch converts x (8192 blocks) + 4 weight matrices (1024 blocks each)
__global__ __launch_bounds__(256)
void cvt_all(const float* __restrict__ x,  const float* __restrict__ qw,
             const float* __restrict__ kw, const float* __restrict__ vw,
             const float* __restrict__ ow,
             bf16_t* __restrict__ Xb,  bf16_t* __restrict__ QWb,
             bf16_t* __restrict__ KWb, bf16_t* __restrict__ VWb,
             bf16_t* __restrict__ OWb) {
  const int b = blockIdx.x;
  const float* in; bf16_t* out; int g;
  if (b < 8192) { in = x; out = Xb; g = b; }
  else {
    const int w  = (b - 8192) >> 10;
    const int wb = (b - 8192) & 1023;
    switch (w) {
      case 0:  in = qw; out = QWb; break;
      case 1:  in = kw; out = KWb; break;
      case 2:  in = vw; out = VWb; break;
      default: in = ow; out = OWb; break;
    }
    g = wb;
  }
  const int idx = (g * 256 + threadIdx.x) * 4;
  float4 v = *(const float4*)(in + idx);
  bf16x4 o = { (bf16_t)v.x, (bf16_t)v.y, (bf16_t)v.z, (bf16_t)v.w };
  *(bf16x4*)(out + idx) = o;
}

// ---------- Verified 128x128 single-buffer GEMM core (845 TF class) ----------
// 128x128 tile, BK=64, 4 waves (wave tile 64x64), 32KB LDS, 80 VGPR ->
// ~5 co-resident blocks/CU; drain stall at __syncthreads hidden by
// INTER-BLOCK overlap (m114). GEMM ledger (rounds 1-4,7): 6/6 variants that
// reduced blocks/CU (bigger tile, dbuf 64KB, in-flight vmcnt schedules)
// regressed. This structure is the accepted local optimum.
// LDS XOR-8 swizzle: slot c of row r holds global chunk c^(r&7).
// A/B frag: m=lane&31, k=(lane>>5)*8+j. C/D: col=lane&31,
// row=(reg&3)+8*(reg>>2)+4*(lane>>5)  [m74/m101].
template <typename OutT>
__device__ __forceinline__ void gemm128_core(
    const bf16_t* __restrict__ A, const bf16_t* __restrict__ B,
    OutT* __restrict__ C, float scl)
{
  constexpr int Kdim = DM;
  __shared__ __attribute__((aligned(16))) bf16_t sA[128 * 64];   // 16 KB
  __shared__ __attribute__((aligned(16))) bf16_t sB[128 * 64];   // 16 KB

  const int tid  = threadIdx.x;
  const int wave = tid >> 6;
  const int lane = tid & 63;
  const int l31  = lane & 31;
  const int half = lane >> 5;
  const int wr   = (wave >> 1) * 64;
  const int wc   = (wave & 1) * 64;

  const int gc = (lane & 7) ^ ((lane >> 3) & 7);   // swizzled fetch chunk
  const size_t arow0 = (size_t)blockIdx.x * 128 + wave * 32 + (lane >> 3);
  const size_t brow0 = (size_t)blockIdx.y * 128 + wave * 32 + (lane >> 3);
  const bf16_t* Ag = A + arow0 * Kdim + gc * 8;
  const bf16_t* Bg = B + brow0 * Kdim + gc * 8;
  bf16_t* sAw = sA + wave * 32 * 64;
  bf16_t* sBw = sB + wave * 32 * 64;

  floatx16 acc[2][2];
  #pragma unroll
  for (int i = 0; i < 2; ++i)
    #pragma unroll
    for (int j = 0; j < 2; ++j)
      acc[i][j] = (floatx16)(0.0f);

  const int sw = l31 & 7;                 // read-side swizzle key

  for (int ko = 0; ko < Kdim; ko += 64) {
    #pragma unroll
    for (int n = 0; n < 4; ++n) {
      async_ld16(sAw + n * 512, Ag + (size_t)n * 8 * Kdim + ko);
      async_ld16(sBw + n * 512, Bg + (size_t)n * 8 * Kdim + ko);
    }
    __syncthreads();   // drains vmcnt, then barrier

    #pragma unroll
    for (int s = 0; s < 4; ++s) {         // four K=16 sub-steps
      const int ck   = s * 2 + half;
      const int slot = (ck ^ sw) * 8;
      bf16x8 af[2], bfr[2];
      #pragma unroll
      for (int mi = 0; mi < 2; ++mi)
        af[mi] = *(const bf16x8*)&sA[(wr + mi * 32 + l31) * 64 + slot];
      #pragma unroll
      for (int ni = 0; ni < 2; ++ni)
        bfr[ni] = *(const bf16x8*)&sB[(wc + ni * 32 + l31) * 64 + slot];

      #pragma unroll
      for (int mi = 0; mi < 2; ++mi)
        #pragma unroll
        for (int ni = 0; ni < 2; ++ni)
          acc[mi][ni] = __builtin_amdgcn_mfma_f32_32x32x16_bf16(af[mi], bfr[ni], acc[mi][ni], 0, 0, 0);
    }

    __syncthreads();   // protect LDS before next stage overwrites
  }

  const int crow0 = blockIdx.x * 128 + wr + 4 * half;
  const int ccol0 = blockIdx.y * 128 + wc + l31;
  #pragma unroll
  for (int mi = 0; mi < 2; ++mi)
    #pragma unroll
    for (int ni = 0; ni < 2; ++ni)
      #pragma unroll
      for (int r = 0; r < 16; ++r) {
        const int row = crow0 + mi * 32 + (r & 3) + 8 * (r >> 2);
        C[(size_t)row * DM + (ccol0 + ni * 32)] = (OutT)(acc[mi][ni][r] * scl);
      }
}

__global__ __launch_bounds__(256)
void gemm_proj(const bf16_t* __restrict__ A, const bf16_t* __restrict__ B,
               bf16_t* __restrict__ C, float scl)
{
  gemm128_core<bf16_t>(A, B, C, scl);
}

__global__ __launch_bounds__(256)
void gemm_outk(const bf16_t* __restrict__ A, const bf16_t* __restrict__ B,
               float* __restrict__ C)
{
  gemm128_core<float>(A, B, C, 1.0f);
}

// ---------- Attention: 1 wave/query, 2-STREAM IN-REGISTER SPLIT (round-8 verified) ----------
// Attn ladder: 41.3 (4-way LDS split) -> 43.5 (1-wave online) -> ~36 (THIS) ->
// 53.3 (round-9 full-score, REFUTED: VGPR 92 serialized the "independent"
// loads; V-after-softmax exposed a second latency hump). Mechanism that works:
// V-loads PAIRED with K-loads (V latency hides under the score chain) + two
// independent online states (even/odd t) halving the serial chain + pair-wise
// X/Y depth-1 prefetch. ~116-128 VGPR -> 4 waves/SIMD (m69 step at 128).
// Pushing MLP higher hits the register wall (round 9); cutting VGPR lengthens
// the chain (round 7). This is the family's local optimum.
// Balanced XCD interleave: XCD x gets chunks {x,8+x,16+x,24+x} of 256 queries
// -> equal sum-npos per XCD. Lane L owns dims [16L,16L+16); Q pre-scaled.
__global__ __launch_bounds__(256)
void dilated_attn(const bf16_t* __restrict__ Q, const bf16_t* __restrict__ K,
                  const bf16_t* __restrict__ V, bf16_t* O)
{
  const int lane = threadIdx.x & 63;
  const int wv   = threadIdx.x >> 6;   // 0..3
  const int bid  = blockIdx.x;         // 0..2047
  const int jj   = bid >> 3;
  const int chunk= (bid & 7) + ((jj >> 6) << 3);       // 0..31
  const int i    = chunk * 256 + (jj & 63) * 4 + wv;   // query index
  const size_t base = (size_t)i * DM + lane * 16;

  bf16x8 q0 = *(const bf16x8*)(Q + base);
  bf16x8 q1 = *(const bf16x8*)(Q + base + 8);
  float qf[16];
  #pragma unroll
  for (int j = 0; j < 8; ++j) { qf[j] = (float)q0[j]; qf[j + 8] = (float)q1[j]; }

  // npos = 1 (i==0) else floor(log2 i) + 2   (wave-uniform); max 14
  const int npos = (i == 0) ? 1 : (33 - __builtin_clz((unsigned)i));
  auto pos_addr = [&](int t) -> size_t {
    const int off = (t == 0) ? 0 : (1 << (t - 1));
    return (size_t)(i - off) * DM + lane * 16;
  };
  auto ld_pos = [&](int t, bf16x8& k0, bf16x8& k1, bf16x8& v0, bf16x8& v1) {
    const size_t a = pos_addr(t);
    k0 = *(const bf16x8*)(K + a); k1 = *(const bf16x8*)(K + a + 8);
    v0 = *(const bf16x8*)(V + a); v1 = *(const bf16x8*)(V + a + 8);
  };

  // two independent online-softmax states: E (even t), D (odd t)
  float mE = -INFINITY, lE = 0.0f, mD = -INFINITY, lD = 0.0f;
  float aE[16], aD[16];
  #pragma unroll
  for (int j = 0; j < 16; ++j) { aE[j] = 0.0f; aD[j] = 0.0f; }

  auto step = [&](float& m, float& l, float* acc,
                  const bf16x8& k0, const bf16x8& k1,
                  const bf16x8& v0, const bf16x8& v1) {
    float sc = 0.0f;
    #pragma unroll
    for (int j = 0; j < 8; ++j) sc += qf[j] * (float)k0[j] + qf[j + 8] * (float)k1[j];
    sc += __shfl_xor(sc, 1, 64);         // sum across the 4 lanes of this head
    sc += __shfl_xor(sc, 2, 64);
    const float mn = fmaxf(m, sc);
    const float co = __expf(m - mn);
    const float w  = __expf(sc - mn);
    l = l * co + w;
    m = mn;
    #pragma unroll
    for (int j = 0; j < 8; ++j) {
      acc[j]     = acc[j]     * co + w * (float)v0[j];
      acc[j + 8] = acc[j + 8] * co + w * (float)v1[j];
    }
  };

  // pair pipeline: X holds pair (t, t+1), Y holds pair (t+2, t+3)
  bf16x8 xk0a, xk1a, xv0a, xv1a, xk0b, xk1b, xv0b, xv1b;
  bf16x8 yk0a, yk1a, yv0a, yv1a, yk0b, yk1b, yv0b, yv1b;

  ld_pos(0, xk0a, xk1a, xv0a, xv1a);
  if (1 < npos) ld_pos(1, xk0b, xk1b, xv0b, xv1b);

  for (int t = 0; ; t += 4) {
    const bool pe1 = (t + 2) < npos;     // Y pair exists (wave-uniform)
    if (pe1)            ld_pos(t + 2, yk0a, yk1a, yv0a, yv1a);
    const bool pd1 = (t + 3) < npos;
    if (pd1)            ld_pos(t + 3, yk0b, yk1b, yv0b, yv1b);
    step(mE, lE, aE, xk0a, xk1a, xv0a, xv1a);
    if ((t + 1) < npos) step(mD, lD, aD, xk0b, xk1b, xv0b, xv1b);
    if (!pe1) break;

    const bool pe2 = (t + 4) < npos;     // next X pair exists
    if (pe2)            ld_pos(t + 4, xk0a, xk1a, xv0a, xv1a);
    if ((t + 5) < npos) ld_pos(t + 5, xk0b, xk1b, xv0b, xv1b);
    step(mE, lE, aE, yk0a, yk1a, yv0a, yv1a);
    if (pd1)            step(mD, lD, aD, yk0b, yk1b, yv0b, yv1b);
    if (!pe2) break;
  }

  // in-register merge of D into E (proven identity; npos==1 -> mD=-inf -> cb=0)
  const float mt = fmaxf(mE, mD);
  const float ca = __expf(mE - mt);
  const float cb = __expf(mD - mt);
  const float inv = 1.0f / (lE * ca + lD * cb);
  bf16x8 o0, o1;
  #pragma unroll
  for (int j = 0; j < 8; ++j) {
    o0[j] = (bf16_t)((aE[j]     * ca + aD[j]     * cb) * inv);
    o1[j] = (bf16_t)((aE[j + 8] * ca + aD[j + 8] * cb) * inv);
  }
  *(bf16x8*)(O + base)     = o0;
  *(bf16x8*)(O + base + 8) = o1;
}

extern "C" void kernel_launch(void* const* d_in, const int* in_sizes, int n_in,
                              void* d_out, int out_size, void* d_ws, size_t ws_size,
                              hipStream_t stream) {
  (void)in_sizes; (void)n_in; (void)out_size; (void)ws_size;
  const float* x  = (const float*)d_in[0];
  const float* qw = (const float*)d_in[1];
  const float* kw = (const float*)d_in[2];
  const float* vw = (const float*)d_in[3];
  const float* ow = (const float*)d_in[4];
  // d_in[5] (positions) and d_in[6] (attend_mask) recomputed analytically in-kernel
  float* out = (float*)d_out;

  bf16_t* Xb  = (bf16_t*)d_ws;                       // 8192x1024
  bf16_t* Qb  = Xb  + (size_t)SEQ * DM;
  bf16_t* Kb  = Qb  + (size_t)SEQ * DM;
  bf16_t* Vb  = Kb  + (size_t)SEQ * DM;
  bf16_t* QWb = Vb  + (size_t)SEQ * DM;              // 1024x1024 x4
  bf16_t* KWb = QWb + (size_t)DM * DM;
  bf16_t* VWb = KWb + (size_t)DM * DM;
  bf16_t* OWb = VWb + (size_t)DM * DM;
  bf16_t* AO  = Qb;  // alias Q: each attn wave reads its own q row before writing it

  cvt_all<<<dim3(8192 + 4096), dim3(256), 0, stream>>>(x, qw, kw, vw, ow,
                                                       Xb, QWb, KWb, VWb, OWb);

  dim3 pg(SEQ / 128, DM / 128);
  gemm_proj<<<pg, dim3(256), 0, stream>>>(Xb, QWb, Qb, 0.125f);  // fold 1/sqrt(64)
  gemm_proj<<<pg, dim3(256), 0, stream>>>(Xb, KWb, Kb, 1.0f);
  gemm_proj<<<pg, dim3(256), 0, stream>>>(Xb, VWb, Vb, 1.0f);
  dilated_attn<<<dim3(SEQ / 4), dim3(256), 0, stream>>>(Qb, Kb, Vb, AO);
  gemm_outk<<<pg, dim3(256), 0, stream>>>(AO, OWb, out);
}

// Round 11
// 216.561 us; speedup vs baseline: 1.0616x; 1.0449x over previous
//
#include <hip/hip_runtime.h>
#include <hip/hip_bf16.h>

typedef __bf16 bf16_t;
typedef __bf16 bf16x4 __attribute__((ext_vector_type(4)));
typedef __bf16 bf16x8 __attribute__((ext_vector_type(8)));
typedef float floatx16 __attribute__((ext_vector_type(16)));

#define SEQ    8192
#define DM     1024
#define NHEADS 16
#define HDIM   64

// async global->LDS, 16B per lane; LDS dest is wave-uniform base + lane*16
__device__ __forceinline__ void async_ld16(bf16_t* lds, const bf16_t* g) {
  __builtin_amdgcn_global_load_lds(
      (__attribute__((address_space(1))) void*)g,
      (__attribute__((address_space(3))) void*)lds, 16, 0, 0);
}

// one launch converts x (8192 blocks) + 4 weight matrices (1024 blocks each)
__global__ __launch_bounds__(256)
void cvt_all(const float* __restrict__ x,  const float* __restrict__ qw,
             const float* __restrict__ kw, const float* __restrict__ vw,
             const float* __restrict__ ow,
             bf16_t* __restrict__ Xb,  bf16_t* __restrict__ QWb,
             bf16_t* __restrict__ KWb, bf16_t* __restrict__ VWb,
             bf16_t* __restrict__ OWb) {
  const int b = blockIdx.x;
  const float* in; bf16_t* out; int g;
  if (b < 8192) { in = x; out = Xb; g = b; }
  else {
    const int w  = (b - 8192) >> 10;
    const int wb = (b - 8192) & 1023;
    switch (w) {
      case 0:  in = qw; out = QWb; break;
      case 1:  in = kw; out = KWb; break;
      case 2:  in = vw; out = VWb; break;
      default: in = ow; out = OWb; break;
    }
    g = wb;
  }
  const int idx = (g * 256 + threadIdx.x) * 4;
  float4 v = *(const float4*)(in + idx);
  bf16x4 o = { (bf16_t)v.x, (bf16_t)v.y, (bf16_t)v.z, (bf16_t)v.w };
  *(bf16x4*)(out + idx) = o;
}

// ---------- Verified 128x128 single-buffer GEMM core (845 TF class) ----------
// 128x128 tile, BK=64, 4 waves (wave tile 64x64), 32KB LDS, 80 VGPR ->
// ~5 co-resident blocks/CU; drain stall at __syncthreads hidden by
// INTER-BLOCK overlap (m114). GEMM ledger (rounds 1-4,7): 6/6 variants that
// reduced blocks/CU (bigger tile, dbuf 64KB, in-flight vmcnt schedules)
// regressed. External corroboration: the 8-phase 256^2 template at K=1024
// (m248 grouped-GEMM) also lands at ~848 TF -- at this K the pipeline depth
// doesn't pay; this structure IS the K=1024 ceiling class.
// LDS XOR-8 swizzle: slot c of row r holds global chunk c^(r&7).
// A/B frag: m=lane&31, k=(lane>>5)*8+j. C/D: col=lane&31,
// row=(reg&3)+8*(reg>>2)+4*(lane>>5)  [m74/m101].
template <typename OutT>
__device__ __forceinline__ void gemm128_core(
    const bf16_t* __restrict__ A, const bf16_t* __restrict__ B,
    OutT* __restrict__ C, float scl)
{
  constexpr int Kdim = DM;
  __shared__ __attribute__((aligned(16))) bf16_t sA[128 * 64];   // 16 KB
  __shared__ __attribute__((aligned(16))) bf16_t sB[128 * 64];   // 16 KB

  const int tid  = threadIdx.x;
  const int wave = tid >> 6;
  const int lane = tid & 63;
  const int l31  = lane & 31;
  const int half = lane >> 5;
  const int wr   = (wave >> 1) * 64;
  const int wc   = (wave & 1) * 64;

  const int gc = (lane & 7) ^ ((lane >> 3) & 7);   // swizzled fetch chunk
  const size_t arow0 = (size_t)blockIdx.x * 128 + wave * 32 + (lane >> 3);
  const size_t brow0 = (size_t)blockIdx.y * 128 + wave * 32 + (lane >> 3);
  const bf16_t* Ag = A + arow0 * Kdim + gc * 8;
  const bf16_t* Bg = B + brow0 * Kdim + gc * 8;
  bf16_t* sAw = sA + wave * 32 * 64;
  bf16_t* sBw = sB + wave * 32 * 64;

  floatx16 acc[2][2];
  #pragma unroll
  for (int i = 0; i < 2; ++i)
    #pragma unroll
    for (int j = 0; j < 2; ++j)
      acc[i][j] = (floatx16)(0.0f);

  const int sw = l31 & 7;                 // read-side swizzle key

  for (int ko = 0; ko < Kdim; ko += 64) {
    #pragma unroll
    for (int n = 0; n < 4; ++n) {
      async_ld16(sAw + n * 512, Ag + (size_t)n * 8 * Kdim + ko);
      async_ld16(sBw + n * 512, Bg + (size_t)n * 8 * Kdim + ko);
    }
    __syncthreads();   // drains vmcnt, then barrier

    #pragma unroll
    for (int s = 0; s < 4; ++s) {         // four K=16 sub-steps
      const int ck   = s * 2 + half;
      const int slot = (ck ^ sw) * 8;
      bf16x8 af[2], bfr[2];
      #pragma unroll
      for (int mi = 0; mi < 2; ++mi)
        af[mi] = *(const bf16x8*)&sA[(wr + mi * 32 + l31) * 64 + slot];
      #pragma unroll
      for (int ni = 0; ni < 2; ++ni)
        bfr[ni] = *(const bf16x8*)&sB[(wc + ni * 32 + l31) * 64 + slot];

      #pragma unroll
      for (int mi = 0; mi < 2; ++mi)
        #pragma unroll
        for (int ni = 0; ni < 2; ++ni)
          acc[mi][ni] = __builtin_amdgcn_mfma_f32_32x32x16_bf16(af[mi], bfr[ni], acc[mi][ni], 0, 0, 0);
    }

    __syncthreads();   // protect LDS before next stage overwrites
  }

  const int crow0 = blockIdx.x * 128 + wr + 4 * half;
  const int ccol0 = blockIdx.y * 128 + wc + l31;
  #pragma unroll
  for (int mi = 0; mi < 2; ++mi)
    #pragma unroll
    for (int ni = 0; ni < 2; ++ni)
      #pragma unroll
      for (int r = 0; r < 16; ++r) {
        const int row = crow0 + mi * 32 + (r & 3) + 8 * (r >> 2);
        C[(size_t)row * DM + (ccol0 + ni * 32)] = (OutT)(acc[mi][ni][r] * scl);
      }
}

// QKV: single dispatch, z selects matrix (r5-measured 61.0 us for all three;
// splitting into 3 launches costs ~4-8 us of inter-dispatch gaps -- r5 vs r8).
__global__ __launch_bounds__(256)
void gemm_qkv(const bf16_t* __restrict__ A,
              const bf16_t* __restrict__ Bq, const bf16_t* __restrict__ Bk,
              const bf16_t* __restrict__ Bv,
              bf16_t* __restrict__ Cq, bf16_t* __restrict__ Ck, bf16_t* __restrict__ Cv)
{
  const bf16_t* B = (blockIdx.z == 0) ? Bq : (blockIdx.z == 1) ? Bk : Bv;
  bf16_t*       C = (blockIdx.z == 0) ? Cq : (blockIdx.z == 1) ? Ck : Cv;
  const float scl = (blockIdx.z == 0) ? 0.125f : 1.0f;   // fold 1/sqrt(64) into Q
  gemm128_core<bf16_t>(A, B, C, scl);
}

__global__ __launch_bounds__(256)
void gemm_outk(const bf16_t* __restrict__ A, const bf16_t* __restrict__ B,
               float* __restrict__ C)
{
  gemm128_core<float>(A, B, C, 1.0f);
}

// ---------- Attention: 1 wave/query, 2-STREAM IN-REGISTER SPLIT (round-8 verified) ----------
// Attn ladder: 41.3 (4-way LDS split) -> 43.5 (1-wave online) -> ~36 (THIS) ->
// 53.3 (round-9 full-score, REFUTED: VGPR 92 serialized the "independent"
// loads; V-after-softmax exposed a second latency hump). Mechanism that works:
// V-loads PAIRED with K-loads (V latency hides under the score chain) + two
// independent online states (even/odd t) halving the serial chain + pair-wise
// X/Y depth-1 prefetch. ~116-128 VGPR -> 4 waves/SIMD (m69 step at 128).
// Pushing MLP higher hits the register wall (round 9); cutting VGPR lengthens
// the chain (round 7). This is the family's local optimum.
// Balanced XCD interleave: XCD x gets chunks {x,8+x,16+x,24+x} of 256 queries
// -> equal sum-npos per XCD. Lane L owns dims [16L,16L+16); Q pre-scaled.
__global__ __launch_bounds__(256)
void dilated_attn(const bf16_t* __restrict__ Q, const bf16_t* __restrict__ K,
                  const bf16_t* __restrict__ V, bf16_t* O)
{
  const int lane = threadIdx.x & 63;
  const int wv   = threadIdx.x >> 6;   // 0..3
  const int bid  = blockIdx.x;         // 0..2047
  const int jj   = bid >> 3;
  const int chunk= (bid & 7) + ((jj >> 6) << 3);       // 0..31
  const int i    = chunk * 256 + (jj & 63) * 4 + wv;   // query index
  const size_t base = (size_t)i * DM + lane * 16;

  bf16x8 q0 = *(const bf16x8*)(Q + base);
  bf16x8 q1 = *(const bf16x8*)(Q + base + 8);
  float qf[16];
  #pragma unroll
  for (int j = 0; j < 8; ++j) { qf[j] = (float)q0[j]; qf[j + 8] = (float)q1[j]; }

  // npos = 1 (i==0) else floor(log2 i) + 2   (wave-uniform); max 14
  const int npos = (i == 0) ? 1 : (33 - __builtin_clz((unsigned)i));
  auto pos_addr = [&](int t) -> size_t {
    const int off = (t == 0) ? 0 : (1 << (t - 1));
    return (size_t)(i - off) * DM + lane * 16;
  };
  auto ld_pos = [&](int t, bf16x8& k0, bf16x8& k1, bf16x8& v0, bf16x8& v1) {
    const size_t a = pos_addr(t);
    k0 = *(const bf16x8*)(K + a); k1 = *(const bf16x8*)(K + a + 8);
    v0 = *(const bf16x8*)(V + a); v1 = *(const bf16x8*)(V + a + 8);
  };

  // two independent online-softmax states: E (even t), D (odd t)
  float mE = -INFINITY, lE = 0.0f, mD = -INFINITY, lD = 0.0f;
  float aE[16], aD[16];
  #pragma unroll
  for (int j = 0; j < 16; ++j) { aE[j] = 0.0f; aD[j] = 0.0f; }

  auto step = [&](float& m, float& l, float* acc,
                  const bf16x8& k0, const bf16x8& k1,
                  const bf16x8& v0, const bf16x8& v1) {
    float sc = 0.0f;
    #pragma unroll
    for (int j = 0; j < 8; ++j) sc += qf[j] * (float)k0[j] + qf[j + 8] * (float)k1[j];
    sc += __shfl_xor(sc, 1, 64);         // sum across the 4 lanes of this head
    sc += __shfl_xor(sc, 2, 64);
    const float mn = fmaxf(m, sc);
    const float co = __expf(m - mn);
    const float w  = __expf(sc - mn);
    l = l * co + w;
    m = mn;
    #pragma unroll
    for (int j = 0; j < 8; ++j) {
      acc[j]     = acc[j]     * co + w * (float)v0[j];
      acc[j + 8] = acc[j + 8] * co + w * (float)v1[j];
    }
  };

  // pair pipeline: X holds pair (t, t+1), Y holds pair (t+2, t+3)
  bf16x8 xk0a, xk1a, xv0a, xv1a, xk0b, xk1b, xv0b, xv1b;
  bf16x8 yk0a, yk1a, yv0a, yv1a, yk0b, yk1b, yv0b, yv1b;

  ld_pos(0, xk0a, xk1a, xv0a, xv1a);
  if (1 < npos) ld_pos(1, xk0b, xk1b, xv0b, xv1b);

  for (int t = 0; ; t += 4) {
    const bool pe1 = (t + 2) < npos;     // Y pair exists (wave-uniform)
    if (pe1)            ld_pos(t + 2, yk0a, yk1a, yv0a, yv1a);
    const bool pd1 = (t + 3) < npos;
    if (pd1)            ld_pos(t + 3, yk0b, yk1b, yv0b, yv1b);
    step(mE, lE, aE, xk0a, xk1a, xv0a, xv1a);
    if ((t + 1) < npos) step(mD, lD, aD, xk0b, xk1b, xv0b, xv1b);
    if (!pe1) break;

    const bool pe2 = (t + 4) < npos;     // next X pair exists
    if (pe2)            ld_pos(t + 4, xk0a, xk1a, xv0a, xv1a);
    if ((t + 5) < npos) ld_pos(t + 5, xk0b, xk1b, xv0b, xv1b);
    step(mE, lE, aE, yk0a, yk1a, yv0a, yv1a);
    if (pd1)            step(mD, lD, aD, yk0b, yk1b, yv0b, yv1b);
    if (!pe2) break;
  }

  // in-register merge of D into E (proven identity; npos==1 -> mD=-inf -> cb=0)
  const float mt = fmaxf(mE, mD);
  const float ca = __expf(mE - mt);
  const float cb = __expf(mD - mt);
  const float inv = 1.0f / (lE * ca + lD * cb);
  bf16x8 o0, o1;
  #pragma unroll
  for (int j = 0; j < 8; ++j) {
    o0[j] = (bf16_t)((aE[j]     * ca + aD[j]     * cb) * inv);
    o1[j] = (bf16_t)((aE[j + 8] * ca + aD[j + 8] * cb) * inv);
  }
  *(bf16x8*)(O + base)     = o0;
  *(bf16x8*)(O + base + 8) = o1;
}

extern "C" void kernel_launch(void* const* d_in, const int* in_sizes, int n_in,
                              void* d_out, int out_size, void* d_ws, size_t ws_size,
                              hipStream_t stream) {
  (void)in_sizes; (void)n_in; (void)out_size; (void)ws_size;
  const float* x  = (const float*)d_in[0];
  const float* qw = (const float*)d_in[1];
  const float* kw = (const float*)d_in[2];
  const float* vw = (const float*)d_in[3];
  const float* ow = (const float*)d_in[4];
  // d_in[5] (positions) and d_in[6] (attend_mask) recomputed analytically in-kernel
  float* out = (float*)d_out;

  bf16_t* Xb  = (bf16_t*)d_ws;                       // 8192x1024
  bf16_t* Qb  = Xb  + (size_t)SEQ * DM;
  bf16_t* Kb  = Qb  + (size_t)SEQ * DM;
  bf16_t* Vb  = Kb  + (size_t)SEQ * DM;
  bf16_t* QWb = Vb  + (size_t)SEQ * DM;              // 1024x1024 x4
  bf16_t* KWb = QWb + (size_t)DM * DM;
  bf16_t* VWb = KWb + (size_t)DM * DM;
  bf16_t* OWb = VWb + (size_t)DM * DM;
  bf16_t* AO  = Qb;  // alias Q: each attn wave reads its own q row before writing it

  cvt_all<<<dim3(8192 + 4096), dim3(256), 0, stream>>>(x, qw, kw, vw, ow,
                                                       Xb, QWb, KWb, VWb, OWb);

  gemm_qkv<<<dim3(SEQ / 128, DM / 128, 3), dim3(256), 0, stream>>>(Xb, QWb, KWb, VWb, Qb, Kb, Vb);
  dilated_attn<<<dim3(SEQ / 4), dim3(256), 0, stream>>>(Qb, Kb, Vb, AO);
  gemm_outk<<<dim3(SEQ / 128, DM / 128), dim3(256), 0, stream>>>(AO, OWb, out);
}